// Round 23
// baseline (244.977 us; speedup 1.0000x reference)
//
#include <hip/hip_runtime.h>
#include <hip/hip_bf16.h>
#include <stdint.h>
#include <stddef.h>

#define EMBED 2048
#define TLEN  2048
#define BSZ   2
#define NH    32
#define NKV   8
#define HD    64
#define MROWS (BSZ*TLEN)   // 4096
#define KVD   (NKV*HD)     // 512
#define QKVN  3072         // fused QKV column extent / row stride

typedef __attribute__((ext_vector_type(8))) short   s16x8;
typedef __attribute__((ext_vector_type(4))) short   s16x4;
typedef __attribute__((ext_vector_type(8))) __bf16  bf16x8;
typedef __attribute__((ext_vector_type(4))) float   f32x4;
typedef __attribute__((ext_vector_type(2))) unsigned long long u64x2;
typedef __attribute__((ext_vector_type(4))) uint32_t u32x4;

static __device__ __forceinline__ float bf2f(short u) {
  union { float f; uint32_t i; } c; c.i = ((uint32_t)(uint16_t)u) << 16; return c.f;
}
static __device__ __forceinline__ short f2bf(float f) {
  union { float f; uint32_t i; } c; c.f = f;
  uint32_t x = c.i;
  uint32_t r = (x + 0x7fffu + ((x >> 16) & 1u)) >> 16;  // RNE
  return (short)(uint16_t)r;
}
static __device__ __forceinline__ bf16x8 as_bf16x8(s16x8 s) {
  return __builtin_bit_cast(bf16x8, s);
}
static __device__ __forceinline__ bf16x8 mk8(unsigned long long a, unsigned long long b) {
  u64x2 t; t.x = a; t.y = b;
  return __builtin_bit_cast(bf16x8, t);
}
static __device__ __forceinline__ bf16x8 mk8w(uint32_t w0, uint32_t w1,
                                              uint32_t w2, uint32_t w3) {
  u32x4 t; t.x = w0; t.y = w1; t.z = w2; t.w = w3;
  return __builtin_bit_cast(bf16x8, t);
}

// ---------------------------------------------------------------------------
// Fused prep: all weight transposes + x cast + rope table in ONE launch.
__device__ __forceinline__ void transpose_tile(
    const float* __restrict__ W, short* __restrict__ Wt, int N,
    int bx, int by, int tx, int ty) {
  __shared__ float tile[32][33];
  const int n0 = bx * 32, k0 = by * 32;
  #pragma unroll
  for (int i = 0; i < 32; i += 8)
    tile[ty + i][tx] = W[(size_t)(k0 + ty + i) * N + n0 + tx];
  __syncthreads();
  #pragma unroll
  for (int i = 0; i < 32; i += 8)
    Wt[(size_t)(n0 + ty + i) * 2048 + k0 + tx] = f2bf(tile[tx][ty + i]);
}

__global__ __launch_bounds__(256) void prep_kernel(
    const float* __restrict__ Wq, const float* __restrict__ Wk,
    const float* __restrict__ Wv, const float* __restrict__ Wo,
    const float* __restrict__ x,
    short* __restrict__ WqkvT, short* __restrict__ WoT,
    short* __restrict__ xb, float2* __restrict__ tab) {
  const int bid = blockIdx.x;
  const int tid = threadIdx.x;
  const int tx = tid & 31, ty = tid >> 5;
  if (bid < 4096) {
    transpose_tile(Wq, WqkvT, 2048, bid & 63, bid >> 6, tx, ty);
  } else if (bid < 5120) {
    const int l = bid - 4096;
    transpose_tile(Wk, WqkvT + (size_t)2048 * 2048, 512, l & 15, l >> 4, tx, ty);
  } else if (bid < 6144) {
    const int l = bid - 5120;
    transpose_tile(Wv, WqkvT + (size_t)2560 * 2048, 512, l & 15, l >> 4, tx, ty);
  } else if (bid < 10240) {
    const int l = bid - 6144;
    transpose_tile(Wo, WoT, 2048, l & 63, l >> 6, tx, ty);
  } else if (bid < 18432) {
    const int i = ((bid - 10240) * 256 + tid) * 4;
    f32x4 v = *(const f32x4*)(x + i);
    s16x4 o = { f2bf(v.x), f2bf(v.y), f2bf(v.z), f2bf(v.w) };
    *(s16x4*)(xb + i) = o;
  } else {
    const int idx = (bid - 18432) * 256 + tid;    // 0..65535
    const int t = idx >> 5, i = idx & 31;
    float ang = (float)t * powf(10000.0f, -(float)i / 32.0f);
    float c, s;
    sincosf(ang, &c, &s);
    tab[idx] = make_float2(c, s);
  }
}

// ---------------------------------------------------------------------------
// Vectorized RoPE over the packed QKV buffer: cols [0,2560) of each 3072-row.
__global__ __launch_bounds__(256) void rope_fused_kernel(
    short* __restrict__ QKV, const float2* __restrict__ tab) {
  const int idx = blockIdx.x * 256 + threadIdx.x;   // 0 .. 4096*320-1
  const int row = idx / 320;
  const int c8 = (idx - row * 320) * 8;             // 0..2552, step 8
  const float QSC = 0.125f * 1.44269504088896340736f;
  const float sc = (c8 < 2048) ? QSC : 1.0f;
  const int t = row & (TLEN - 1);
  const int i0 = (c8 & 63) >> 1;                    // multiple of 4
  const float4* tp = (const float4*)&tab[(t << 5) + i0];
  const float4 cs01 = tp[0], cs23 = tp[1];
  short* p = QKV + (size_t)row * QKVN + c8;
  s16x8 v = *(const s16x8*)p;
  const float e0 = bf2f(v[0]), o0 = bf2f(v[1]), e1 = bf2f(v[2]), o1 = bf2f(v[3]);
  const float e2 = bf2f(v[4]), o2 = bf2f(v[5]), e3 = bf2f(v[6]), o3 = bf2f(v[7]);
  s16x8 r;
  r[0] = f2bf((e0 * cs01.x + o0 * cs01.y) * sc);
  r[1] = f2bf((o0 * cs01.x - e0 * cs01.y) * sc);
  r[2] = f2bf((e1 * cs01.z + o1 * cs01.w) * sc);
  r[3] = f2bf((o1 * cs01.z - e1 * cs01.w) * sc);
  r[4] = f2bf((e2 * cs23.x + o2 * cs23.y) * sc);
  r[5] = f2bf((o2 * cs23.x - e2 * cs23.y) * sc);
  r[6] = f2bf((e3 * cs23.z + o3 * cs23.w) * sc);
  r[7] = f2bf((o3 * cs23.z - e3 * cs23.w) * sc);
  *(s16x8*)p = r;
}

// ---------------------------------------------------------------------------
// C[M=4096][colN] = A[4096][2048] @ Bt[colN][2048]^T + bias; row stride ldc.
// 128x128 tile, BK=32, 4 waves, global_load_lds width=16 staging.
template<bool OUT_F32, bool TRIPLE_BIAS>
__global__ __launch_bounds__(256) void gemm_bt(
    const short* __restrict__ A, const short* __restrict__ Bt,
    const float* __restrict__ b0, const float* __restrict__ b1,
    const float* __restrict__ b2, void* __restrict__ Cout, int ldc) {
  const int K = 2048;
  __shared__ __align__(16) short As[128 * 32];
  __shared__ __align__(16) short Bs[128 * 32];
  int bn = blockIdx.x, bm = blockIdx.y;
  int tid = threadIdx.x;
  int lane = tid & 63, wave = tid >> 6;
  int wr = wave >> 1, wc = wave & 1;
  int fr = lane & 15, fk = lane >> 4;
  f32x4 acc[4][4] = {};
  const short* Ab = A + (size_t)bm * 128 * K;
  const short* Bb = Bt + (size_t)bn * 128 * K;
  for (int kt = 0; kt < K; kt += 32) {
    #pragma unroll
    for (int ii = 0; ii < 2; ++ii) {
      const int i = wave * 2 + ii;
      const int r = i * 16 + (lane >> 2);
      const int c = lane & 3;
      const size_t go = (size_t)r * K + kt + c * 8;
      __builtin_amdgcn_global_load_lds(
          (const __attribute__((address_space(1))) void*)(Ab + go),
          (__attribute__((address_space(3))) void*)&As[i * 512], 16, 0, 0);
      __builtin_amdgcn_global_load_lds(
          (const __attribute__((address_space(1))) void*)(Bb + go),
          (__attribute__((address_space(3))) void*)&Bs[i * 512], 16, 0, 0);
    }
    __syncthreads();
    bf16x8 af[4], bfr[4];
    #pragma unroll
    for (int m = 0; m < 4; ++m)
      af[m] = as_bf16x8(*(const s16x8*)&As[(wr * 64 + m * 16 + fr) * 32 + fk * 8]);
    #pragma unroll
    for (int n = 0; n < 4; ++n)
      bfr[n] = as_bf16x8(*(const s16x8*)&Bs[(wc * 64 + n * 16 + fr) * 32 + fk * 8]);
    __builtin_amdgcn_s_setprio(1);
    #pragma unroll
    for (int m = 0; m < 4; ++m)
      #pragma unroll
      for (int n = 0; n < 4; ++n)
        acc[m][n] = __builtin_amdgcn_mfma_f32_16x16x32_bf16(af[m], bfr[n], acc[m][n], 0, 0, 0);
    __builtin_amdgcn_s_setprio(0);
    __syncthreads();
  }
  int row0 = bm * 128 + wr * 64;
  int col0 = bn * 128 + wc * 64;
  #pragma unroll
  for (int n = 0; n < 4; ++n) {
    int col = col0 + n * 16 + fr;
    float bv;
    if constexpr (TRIPLE_BIAS)
      bv = (col < 2048) ? b0[col] : ((col < 2560) ? b1[col - 2048] : b2[col - 2560]);
    else
      bv = b0[col];
    #pragma unroll
    for (int m = 0; m < 4; ++m)
      #pragma unroll
      for (int j = 0; j < 4; ++j) {
        int row = row0 + m * 16 + fk * 4 + j;
        float v = acc[m][n][j] + bv;
        if constexpr (OUT_F32) ((float*)Cout)[(size_t)row * ldc + col] = v;
        else                   ((short*)Cout)[(size_t)row * ldc + col] = f2bf(v);
      }
  }
}

// ---------------------------------------------------------------------------
// Flash attention, causal, GQA. 4 waves, 64 q-rows/block, KVBLK=64, q-tile
// pair (p, 31-p): 33 kv-tiles/block uniform, 1024 blocks = 4/CU (R20 base).
// NEW: K and V double-buffered in LDS; ONE barrier per tile; next-tile global
// loads issued before compute (T14 async split), ds_writes after compute.
// Invariant: tile n reads buf[cur], writes buf[cur^1]; tile n-1's reads of
// buf[cur^1] are separated from these writes by the single barrier.
// Per-q-row math identical to R20 -> bit-identical output.
__global__ __launch_bounds__(256) void attn_kernel(
    const short* __restrict__ Q, const short* __restrict__ Kx,
    const short* __restrict__ Vx, short* __restrict__ O) {
  const int pr = blockIdx.x;           // 0..15
  const int bh = blockIdx.y;           // 0..63
  const int b = bh >> 5, h = bh & 31, kvh = h >> 2;
  const int tid = threadIdx.x;
  const int lane = tid & 63, wave = tid >> 6;
  const int fr = lane & 15, fk = lane >> 4;

  __shared__ __align__(16) short Ks[2][64][72];   // [buf][kpos][d]
  __shared__ __align__(16) short VS[2][4160];     // [buf] permuted subtiles

  const short* Kbase = Kx + (size_t)b * TLEN * QKVN + kvh * HD;
  const short* Vbase = Vx + (size_t)b * TLEN * QKVN + kvh * HD;

  const int srow = tid >> 3;           // 0..31
  const int scb  = (tid & 7) << 3;
  const int vd0  = scb >> 4;
  const int vco  = scb & 15;
  // permuted slot for kpos r (r<32): p = ((r>>2)&3)<<3 | ((r>>4)&1)<<2 | (r&3)
  const int p0 = (((srow >> 2) & 3) << 3) | (((srow >> 4) & 1) << 2) | (srow & 3);
  const int vaddr0 = vd0 * 1040 + ((p0 >> 2) << 6) + ((p0 & 3) << 4) + vco;
  const int vaddr1 = vaddr0 + 512;     // r+32 -> slot p+32
  const unsigned trbase = (unsigned)(unsigned long long)&VS[0][fk * 128 + fr * 4];
  const bf16x8 ones = mk8(0x3F803F803F803F80ULL, 0x3F803F803F803F80ULL);

#define TRREAD(dst, BASE, OFF) asm volatile("ds_read_b64_tr_b16 %0, %1 offset:" OFF \
    : "=v"(dst) : "v"(BASE) : "memory")
#define CVTPK(d, lo, hi) asm volatile("v_cvt_pk_bf16_f32 %0, %1, %2" \
    : "=v"(d) : "v"(lo), "v"(hi))

  int cur = 0;

  #pragma unroll 1
  for (int rep = 0; rep < 2; ++rep) {
    const int qt = rep ? (31 - pr) : pr;
    const int q0 = qt * 64;
    const short* Qrow = Q + (size_t)(b * TLEN + q0 + wave * 16 + fr) * QKVN + h * HD;
    const bf16x8 aq0 = as_bf16x8(*(const s16x8*)&Qrow[fk * 8]);
    const bf16x8 aq1 = as_bf16x8(*(const s16x8*)&Qrow[32 + fk * 8]);
    f32x4 oacc[4] = {};
    f32x4 lacc = {};
    float m = -INFINITY;
    const int qloc = wave * 16 + fr;

    // ---- prologue: stage tile 0 into buf[cur] (prev rep's reads are behind
    // the loop's final barrier) ----
    {
      const size_t g0 = (size_t)srow * QKVN + scb;
      const size_t g1 = (size_t)(srow + 32) * QKVN + scb;
      s16x8 ka = *(const s16x8*)&Kbase[g0];
      s16x8 kb = *(const s16x8*)&Kbase[g1];
      s16x8 va = *(const s16x8*)&Vbase[g0];
      s16x8 vb = *(const s16x8*)&Vbase[g1];
      *(s16x8*)&Ks[cur][srow][scb] = ka;
      *(s16x8*)&Ks[cur][srow + 32][scb] = kb;
      *(s16x8*)&VS[cur][vaddr0] = va;
      *(s16x8*)&VS[cur][vaddr1] = vb;
    }
    __syncthreads();

    for (int kv0 = 0; kv0 <= q0; kv0 += 64) {
      const bool more = (kv0 + 64 <= q0);

      // ---- issue next-tile global loads early (hide under compute) ----
      s16x8 ka, kb, va, vb;
      if (more) {
        const size_t g0 = (size_t)(kv0 + 64 + srow) * QKVN + scb;
        const size_t g1 = (size_t)(kv0 + 64 + srow + 32) * QKVN + scb;
        ka = *(const s16x8*)&Kbase[g0];
        kb = *(const s16x8*)&Kbase[g1];
        va = *(const s16x8*)&Vbase[g0];
        vb = *(const s16x8*)&Vbase[g1];
      }

      // ---- S^T = K Q^T : 4 m-tiles from Ks[cur] ----
      f32x4 sacc[4] = {};
      {
        bf16x8 bk0[4], bk1[4];
        #pragma unroll
        for (int mb = 0; mb < 4; ++mb) {
          bk0[mb] = as_bf16x8(*(const s16x8*)&Ks[cur][mb * 16 + fr][fk * 8]);
          bk1[mb] = as_bf16x8(*(const s16x8*)&Ks[cur][mb * 16 + fr][32 + fk * 8]);
        }
        __builtin_amdgcn_s_setprio(1);
        #pragma unroll
        for (int mb = 0; mb < 4; ++mb) {
          sacc[mb] = __builtin_amdgcn_mfma_f32_16x16x32_bf16(bk0[mb], aq0, sacc[mb], 0, 0, 0);
          sacc[mb] = __builtin_amdgcn_mfma_f32_16x16x32_bf16(bk1[mb], aq1, sacc[mb], 0, 0, 0);
        }
        __builtin_amdgcn_s_setprio(0);
      }

      // ---- mask (diag only) + in-register row max ----
      const bool diag = (kv0 == q0);
      float sv[4][4];
      float pm = -INFINITY;
      #pragma unroll
      for (int mb = 0; mb < 4; ++mb)
        #pragma unroll
        for (int j = 0; j < 4; ++j) {
          float v = sacc[mb][j];
          if (diag && (mb * 16 + fk * 4 + j > qloc)) v = -INFINITY;
          sv[mb][j] = v;
          pm = fmaxf(pm, v);
        }
      pm = fmaxf(pm, __shfl_xor(pm, 16, 64));
      pm = fmaxf(pm, __shfl_xor(pm, 32, 64));

      // ---- defer-max rescale (THR = 11.5 in log2 domain) ----
      if (__any(pm > m + 11.5f)) {
        const float mnew = fmaxf(m, pm);
        const float al = exp2f(m - mnew);
        m = mnew;
        lacc[0] *= al; lacc[1] *= al; lacc[2] *= al; lacc[3] *= al;
        #pragma unroll
        for (int db = 0; db < 4; ++db) {
          oacc[db][0] *= al; oacc[db][1] *= al;
          oacc[db][2] *= al; oacc[db][3] *= al;
        }
      }

      // ---- P = exp2(S-m), pack: in-lane B-fragments (V perm-placed) ----
      uint32_t rlo[4], rhi[4];
      #pragma unroll
      for (int mb = 0; mb < 4; ++mb) {
        float e0 = exp2f(sv[mb][0] - m);
        float e1 = exp2f(sv[mb][1] - m);
        float e2 = exp2f(sv[mb][2] - m);
        float e3 = exp2f(sv[mb][3] - m);
        CVTPK(rlo[mb], e0, e1);
        CVTPK(rhi[mb], e2, e3);
      }
      const bf16x8 pB0 = mk8w(rlo[0], rhi[0], rlo[1], rhi[1]);
      const bf16x8 pB1 = mk8w(rlo[2], rhi[2], rlo[3], rhi[3]);

      // ---- PV: O^T += V^T . P^T from VS[cur] ; lsum via ones-MFMA ----
      const unsigned trb = trbase + (unsigned)(cur * 8320);
      unsigned long long t00, t01, t02, t03, t10, t11, t12, t13;
      unsigned long long t20, t21, t22, t23, t30, t31, t32, t33;
      TRREAD(t00, trb, "0");    TRREAD(t01, trb, "128");
      TRREAD(t02, trb, "1024"); TRREAD(t03, trb, "1152");
      TRREAD(t10, trb, "2080"); TRREAD(t11, trb, "2208");
      TRREAD(t12, trb, "3104"); TRREAD(t13, trb, "3232");
      TRREAD(t20, trb, "4160"); TRREAD(t21, trb, "4288");
      TRREAD(t22, trb, "5184"); TRREAD(t23, trb, "5312");
      TRREAD(t30, trb, "6240"); TRREAD(t31, trb, "6368");
      TRREAD(t32, trb, "7264"); TRREAD(t33, trb, "7392");
      asm volatile("s_waitcnt lgkmcnt(0)" ::: "memory");
      __builtin_amdgcn_sched_barrier(0);
      __builtin_amdgcn_s_setprio(1);
      lacc = __builtin_amdgcn_mfma_f32_16x16x32_bf16(ones, pB0, lacc, 0, 0, 0);
      lacc = __builtin_amdgcn_mfma_f32_16x16x32_bf16(ones, pB1, lacc, 0, 0, 0);
      oacc[0] = __builtin_amdgcn_mfma_f32_16x16x32_bf16(mk8(t00, t01), pB0, oacc[0], 0, 0, 0);
      oacc[0] = __builtin_amdgcn_mfma_f32_16x16x32_bf16(mk8(t02, t03), pB1, oacc[0], 0, 0, 0);
      oacc[1] = __builtin_amdgcn_mfma_f32_16x16x32_bf16(mk8(t10, t11), pB0, oacc[1], 0, 0, 0);
      oacc[1] = __builtin_amdgcn_mfma_f32_16x16x32_bf16(mk8(t12, t13), pB1, oacc[1], 0, 0, 0);
      oacc[2] = __builtin_amdgcn_mfma_f32_16x16x32_bf16(mk8(t20, t21), pB0, oacc[2], 0, 0, 0);
      oacc[2] = __builtin_amdgcn_mfma_f32_16x16x32_bf16(mk8(t22, t23), pB1, oacc[2], 0, 0, 0);
      oacc[3] = __builtin_amdgcn_mfma_f32_16x16x32_bf16(mk8(t30, t31), pB0, oacc[3], 0, 0, 0);
      oacc[3] = __builtin_amdgcn_mfma_f32_16x16x32_bf16(mk8(t32, t33), pB1, oacc[3], 0, 0, 0);
      __builtin_amdgcn_s_setprio(0);

      // ---- write next tile into the other buffer, single barrier ----
      if (more) {
        *(s16x8*)&Ks[cur ^ 1][srow][scb] = ka;
        *(s16x8*)&Ks[cur ^ 1][srow + 32][scb] = kb;
        *(s16x8*)&VS[cur ^ 1][vaddr0] = va;
        *(s16x8*)&VS[cur ^ 1][vaddr1] = vb;
      }
      __syncthreads();
      cur ^= 1;
    }

    // ---- epilogue: O^T -> O, one q-row per lane (regs only; no LDS) ----
    {
      const float linv = 1.0f / lacc[0];
      short* orow = O + (size_t)(b * TLEN + q0 + wave * 16 + fr) * EMBED + h * HD + fk * 4;
      #pragma unroll
      for (int db = 0; db < 4; ++db) {
        s16x4 o4 = { f2bf(oacc[db][0] * linv), f2bf(oacc[db][1] * linv),
                     f2bf(oacc[db][2] * linv), f2bf(oacc[db][3] * linv) };
        *(s16x4*)&orow[db * 16] = o4;
      }
    }
  }
#undef TRREAD
#undef CVTPK
}

// ---------------------------------------------------------------------------
extern "C" void kernel_launch(void* const* d_in, const int* in_sizes, int n_in,
                              void* d_out, int out_size, void* d_ws, size_t ws_size,
                              hipStream_t stream) {
  const float* x  = (const float*)d_in[0];
  const float* Wq = (const float*)d_in[1];
  const float* bq = (const float*)d_in[2];
  const float* Wk = (const float*)d_in[3];
  const float* bk = (const float*)d_in[4];
  const float* Wv = (const float*)d_in[5];
  const float* bv = (const float*)d_in[6];
  const float* Wo = (const float*)d_in[7];
  const float* bo = (const float*)d_in[8];
  float* out = (float*)d_out;

  char* ws = (char*)d_ws;
  short* xb    = (short*)(ws);               // 16,777,216
  short* WqkvT = (short*)(ws + 16777216);    // 12,582,912
  short* WoT   = (short*)(ws + 29360128);    //  8,388,608
  short* QKV   = (short*)(ws + 37748736);    // 25,165,824
  short* Ob    = (short*)(ws);               // alias xb (dead after QKV GEMM)
  float2* tab  = (float2*)d_out;             // 512 KB scratch; overwritten at end

  // one fused prep launch: transposes + cast + rope table
  prep_kernel<<<18688, 256, 0, stream>>>(Wq, Wk, Wv, Wo, x, WqkvT, WoT, xb, tab);

  // fused QKV projection (plain epilogue)
  gemm_bt<false, true><<<dim3(QKVN / 128, MROWS / 128), 256, 0, stream>>>(
      xb, WqkvT, bq, bk, bv, QKV, QKVN);

  // single vectorized RoPE pass over Q+K region (Q scaled into exp2 domain)
  rope_fused_kernel<<<(MROWS * 320) / 256, 256, 0, stream>>>(QKV, tab);

  attn_kernel<<<dim3(16, BSZ * NH), 256, 0, stream>>>(
      QKV, QKV + 2048, QKV + 2560, Ob);

  gemm_bt<true, false><<<dim3(EMBED / 128, MROWS / 128), 256, 0, stream>>>(
      Ob, WoT, bo, bo, bo, out, EMBED);
}

// Round 24
// 228.539 us; speedup vs baseline: 1.0719x; 1.0719x over previous
//
#include <hip/hip_runtime.h>
#include <hip/hip_bf16.h>
#include <stdint.h>
#include <stddef.h>

#define EMBED 2048
#define TLEN  2048
#define BSZ   2
#define NH    32
#define NKV   8
#define HD    64
#define MROWS (BSZ*TLEN)   // 4096
#define KVD   (NKV*HD)     // 512
#define QKVN  3072         // fused QKV column extent / row stride

typedef __attribute__((ext_vector_type(8))) short   s16x8;
typedef __attribute__((ext_vector_type(4))) short   s16x4;
typedef __attribute__((ext_vector_type(8))) __bf16  bf16x8;
typedef __attribute__((ext_vector_type(4))) float   f32x4;
typedef __attribute__((ext_vector_type(2))) unsigned long long u64x2;
typedef __attribute__((ext_vector_type(4))) uint32_t u32x4;

static __device__ __forceinline__ float bf2f(short u) {
  union { float f; uint32_t i; } c; c.i = ((uint32_t)(uint16_t)u) << 16; return c.f;
}
static __device__ __forceinline__ short f2bf(float f) {
  union { float f; uint32_t i; } c; c.f = f;
  uint32_t x = c.i;
  uint32_t r = (x + 0x7fffu + ((x >> 16) & 1u)) >> 16;  // RNE
  return (short)(uint16_t)r;
}
static __device__ __forceinline__ bf16x8 as_bf16x8(s16x8 s) {
  return __builtin_bit_cast(bf16x8, s);
}
static __device__ __forceinline__ bf16x8 mk8(unsigned long long a, unsigned long long b) {
  u64x2 t; t.x = a; t.y = b;
  return __builtin_bit_cast(bf16x8, t);
}
static __device__ __forceinline__ bf16x8 mk8w(uint32_t w0, uint32_t w1,
                                              uint32_t w2, uint32_t w3) {
  u32x4 t; t.x = w0; t.y = w1; t.z = w2; t.w = w3;
  return __builtin_bit_cast(bf16x8, t);
}

// ---------------------------------------------------------------------------
// Fused prep: all weight transposes + x cast + rope table in ONE launch.
__device__ __forceinline__ void transpose_tile(
    const float* __restrict__ W, short* __restrict__ Wt, int N,
    int bx, int by, int tx, int ty) {
  __shared__ float tile[32][33];
  const int n0 = bx * 32, k0 = by * 32;
  #pragma unroll
  for (int i = 0; i < 32; i += 8)
    tile[ty + i][tx] = W[(size_t)(k0 + ty + i) * N + n0 + tx];
  __syncthreads();
  #pragma unroll
  for (int i = 0; i < 32; i += 8)
    Wt[(size_t)(n0 + ty + i) * 2048 + k0 + tx] = f2bf(tile[tx][ty + i]);
}

__global__ __launch_bounds__(256) void prep_kernel(
    const float* __restrict__ Wq, const float* __restrict__ Wk,
    const float* __restrict__ Wv, const float* __restrict__ Wo,
    const float* __restrict__ x,
    short* __restrict__ WqkvT, short* __restrict__ WoT,
    short* __restrict__ xb, float2* __restrict__ tab) {
  const int bid = blockIdx.x;
  const int tid = threadIdx.x;
  const int tx = tid & 31, ty = tid >> 5;
  if (bid < 4096) {
    transpose_tile(Wq, WqkvT, 2048, bid & 63, bid >> 6, tx, ty);
  } else if (bid < 5120) {
    const int l = bid - 4096;
    transpose_tile(Wk, WqkvT + (size_t)2048 * 2048, 512, l & 15, l >> 4, tx, ty);
  } else if (bid < 6144) {
    const int l = bid - 5120;
    transpose_tile(Wv, WqkvT + (size_t)2560 * 2048, 512, l & 15, l >> 4, tx, ty);
  } else if (bid < 10240) {
    const int l = bid - 6144;
    transpose_tile(Wo, WoT, 2048, l & 63, l >> 6, tx, ty);
  } else if (bid < 18432) {
    const int i = ((bid - 10240) * 256 + tid) * 4;
    f32x4 v = *(const f32x4*)(x + i);
    s16x4 o = { f2bf(v.x), f2bf(v.y), f2bf(v.z), f2bf(v.w) };
    *(s16x4*)(xb + i) = o;
  } else {
    const int idx = (bid - 18432) * 256 + tid;    // 0..65535
    const int t = idx >> 5, i = idx & 31;
    float ang = (float)t * powf(10000.0f, -(float)i / 32.0f);
    float c, s;
    sincosf(ang, &c, &s);
    tab[idx] = make_float2(c, s);
  }
}

// ---------------------------------------------------------------------------
// Vectorized RoPE over the packed QKV buffer: cols [0,2560) of each 3072-row.
// One thread = 8 shorts = 4 interleaved pairs; inverse rotation (np ref
// convention, verified R11); Q cols (<2048) scaled by 0.125*log2e.
__global__ __launch_bounds__(256) void rope_fused_kernel(
    short* __restrict__ QKV, const float2* __restrict__ tab) {
  const int idx = blockIdx.x * 256 + threadIdx.x;   // 0 .. 4096*320-1
  const int row = idx / 320;
  const int c8 = (idx - row * 320) * 8;             // 0..2552, step 8
  const float QSC = 0.125f * 1.44269504088896340736f;
  const float sc = (c8 < 2048) ? QSC : 1.0f;
  const int t = row & (TLEN - 1);
  const int i0 = (c8 & 63) >> 1;                    // multiple of 4
  const float4* tp = (const float4*)&tab[(t << 5) + i0];
  const float4 cs01 = tp[0], cs23 = tp[1];
  short* p = QKV + (size_t)row * QKVN + c8;
  s16x8 v = *(const s16x8*)p;
  const float e0 = bf2f(v[0]), o0 = bf2f(v[1]), e1 = bf2f(v[2]), o1 = bf2f(v[3]);
  const float e2 = bf2f(v[4]), o2 = bf2f(v[5]), e3 = bf2f(v[6]), o3 = bf2f(v[7]);
  s16x8 r;
  r[0] = f2bf((e0 * cs01.x + o0 * cs01.y) * sc);
  r[1] = f2bf((o0 * cs01.x - e0 * cs01.y) * sc);
  r[2] = f2bf((e1 * cs01.z + o1 * cs01.w) * sc);
  r[3] = f2bf((o1 * cs01.z - e1 * cs01.w) * sc);
  r[4] = f2bf((e2 * cs23.x + o2 * cs23.y) * sc);
  r[5] = f2bf((o2 * cs23.x - e2 * cs23.y) * sc);
  r[6] = f2bf((e3 * cs23.z + o3 * cs23.w) * sc);
  r[7] = f2bf((o3 * cs23.z - e3 * cs23.w) * sc);
  *(s16x8*)p = r;
}

// ---------------------------------------------------------------------------
// C[M=4096][colN] = A[4096][2048] @ Bt[colN][2048]^T + bias; row stride ldc.
// 128x128 tile, BK=32, 4 waves, global_load_lds width=16 staging.
// Plain epilogue (R16-proven ~860 TF structure).
template<bool OUT_F32, bool TRIPLE_BIAS>
__global__ __launch_bounds__(256) void gemm_bt(
    const short* __restrict__ A, const short* __restrict__ Bt,
    const float* __restrict__ b0, const float* __restrict__ b1,
    const float* __restrict__ b2, void* __restrict__ Cout, int ldc) {
  const int K = 2048;
  __shared__ __align__(16) short As[128 * 32];
  __shared__ __align__(16) short Bs[128 * 32];
  int bn = blockIdx.x, bm = blockIdx.y;
  int tid = threadIdx.x;
  int lane = tid & 63, wave = tid >> 6;
  int wr = wave >> 1, wc = wave & 1;
  int fr = lane & 15, fk = lane >> 4;
  f32x4 acc[4][4] = {};
  const short* Ab = A + (size_t)bm * 128 * K;
  const short* Bb = Bt + (size_t)bn * 128 * K;
  for (int kt = 0; kt < K; kt += 32) {
    #pragma unroll
    for (int ii = 0; ii < 2; ++ii) {
      const int i = wave * 2 + ii;
      const int r = i * 16 + (lane >> 2);
      const int c = lane & 3;
      const size_t go = (size_t)r * K + kt + c * 8;
      __builtin_amdgcn_global_load_lds(
          (const __attribute__((address_space(1))) void*)(Ab + go),
          (__attribute__((address_space(3))) void*)&As[i * 512], 16, 0, 0);
      __builtin_amdgcn_global_load_lds(
          (const __attribute__((address_space(1))) void*)(Bb + go),
          (__attribute__((address_space(3))) void*)&Bs[i * 512], 16, 0, 0);
    }
    __syncthreads();
    bf16x8 af[4], bfr[4];
    #pragma unroll
    for (int m = 0; m < 4; ++m)
      af[m] = as_bf16x8(*(const s16x8*)&As[(wr * 64 + m * 16 + fr) * 32 + fk * 8]);
    #pragma unroll
    for (int n = 0; n < 4; ++n)
      bfr[n] = as_bf16x8(*(const s16x8*)&Bs[(wc * 64 + n * 16 + fr) * 32 + fk * 8]);
    __builtin_amdgcn_s_setprio(1);
    #pragma unroll
    for (int m = 0; m < 4; ++m)
      #pragma unroll
      for (int n = 0; n < 4; ++n)
        acc[m][n] = __builtin_amdgcn_mfma_f32_16x16x32_bf16(af[m], bfr[n], acc[m][n], 0, 0, 0);
    __builtin_amdgcn_s_setprio(0);
    __syncthreads();
  }
  int row0 = bm * 128 + wr * 64;
  int col0 = bn * 128 + wc * 64;
  #pragma unroll
  for (int n = 0; n < 4; ++n) {
    int col = col0 + n * 16 + fr;
    float bv;
    if constexpr (TRIPLE_BIAS)
      bv = (col < 2048) ? b0[col] : ((col < 2560) ? b1[col - 2048] : b2[col - 2560]);
    else
      bv = b0[col];
    #pragma unroll
    for (int m = 0; m < 4; ++m)
      #pragma unroll
      for (int j = 0; j < 4; ++j) {
        int row = row0 + m * 16 + fk * 4 + j;
        float v = acc[m][n][j] + bv;
        if constexpr (OUT_F32) ((float*)Cout)[(size_t)row * ldc + col] = v;
        else                   ((short*)Cout)[(size_t)row * ldc + col] = f2bf(v);
      }
  }
}

// ---------------------------------------------------------------------------
// Flash attention (best measured config, R20: 93.5 us). 4 waves, 64 q-rows/
// block, KVBLK=64, q-tile pair (p, 31-p): 33 kv-tiles/block static-uniform,
// 1024 blocks. Swapped-operand S^T = mfma(K,Q); K staged in LDS (coalesced);
// V staged with PERMUTED subtile placement so each lane's cvt_pk words ARE
// the P^T B-fragments (zero cross-lane ops); PV via ds_read_b64_tr_b16.
// exp2-domain softmax, defer-max, ones-MFMA row sums.
__global__ __launch_bounds__(256) void attn_kernel(
    const short* __restrict__ Q, const short* __restrict__ Kx,
    const short* __restrict__ Vx, short* __restrict__ O) {
  const int pr = blockIdx.x;           // 0..15
  const int bh = blockIdx.y;           // 0..63
  const int b = bh >> 5, h = bh & 31, kvh = h >> 2;
  const int tid = threadIdx.x;
  const int lane = tid & 63, wave = tid >> 6;
  const int fr = lane & 15, fk = lane >> 4;

  __shared__ __align__(16) short Ks[64][72];    // [kpos][d], 2-way padded
  __shared__ __align__(16) short VS[4 * 1040];  // tr-read subtiled V (permuted)

  const short* Kbase = Kx + (size_t)b * TLEN * QKVN + kvh * HD;
  const short* Vbase = Vx + (size_t)b * TLEN * QKVN + kvh * HD;

  const int srow = tid >> 3;           // 0..31
  const int scb  = (tid & 7) << 3;
  const int vd0  = scb >> 4;
  const int vco  = scb & 15;
  // permuted slot for kpos r (r<32): p = ((r>>2)&3)<<3 | ((r>>4)&1)<<2 | (r&3)
  const int p0 = (((srow >> 2) & 3) << 3) | (((srow >> 4) & 1) << 2) | (srow & 3);
  const int vaddr0 = vd0 * 1040 + ((p0 >> 2) << 6) + ((p0 & 3) << 4) + vco;
  const int vaddr1 = vaddr0 + 512;     // r+32 -> slot p+32
  const unsigned trb = (unsigned)(unsigned long long)&VS[fk * 128 + fr * 4];
  const bf16x8 ones = mk8(0x3F803F803F803F80ULL, 0x3F803F803F803F80ULL);

#define TRREAD(dst, OFF) asm volatile("ds_read_b64_tr_b16 %0, %1 offset:" OFF \
    : "=v"(dst) : "v"(trb) : "memory")
#define CVTPK(d, lo, hi) asm volatile("v_cvt_pk_bf16_f32 %0, %1, %2" \
    : "=v"(d) : "v"(lo), "v"(hi))

  #pragma unroll 1
  for (int rep = 0; rep < 2; ++rep) {
    const int qt = rep ? (31 - pr) : pr;
    const int q0 = qt * 64;
    const short* Qrow = Q + (size_t)(b * TLEN + q0 + wave * 16 + fr) * QKVN + h * HD;
    const bf16x8 aq0 = as_bf16x8(*(const s16x8*)&Qrow[fk * 8]);
    const bf16x8 aq1 = as_bf16x8(*(const s16x8*)&Qrow[32 + fk * 8]);
    f32x4 oacc[4] = {};
    f32x4 lacc = {};
    float m = -INFINITY;
    const int qloc = wave * 16 + fr;

    for (int kv0 = 0; kv0 <= q0; kv0 += 64) {
      // ---- stage K (row-major padded) and V (permuted subtiles) ----
      #pragma unroll
      for (int it = 0; it < 2; ++it) {
        const int r = srow + it * 32;
        const size_t gro = (size_t)(kv0 + r) * QKVN + scb;
        *(s16x8*)&Ks[r][scb] = *(const s16x8*)&Kbase[gro];
        s16x8 vv = *(const s16x8*)&Vbase[gro];
        *(s16x8*)&VS[it ? vaddr1 : vaddr0] = vv;
      }
      __syncthreads();

      // ---- S^T = K Q^T : 4 m-tiles (k-blocks of 16) ----
      f32x4 sacc[4] = {};
      {
        bf16x8 bk0[4], bk1[4];
        #pragma unroll
        for (int mb = 0; mb < 4; ++mb) {
          bk0[mb] = as_bf16x8(*(const s16x8*)&Ks[mb * 16 + fr][fk * 8]);
          bk1[mb] = as_bf16x8(*(const s16x8*)&Ks[mb * 16 + fr][32 + fk * 8]);
        }
        __builtin_amdgcn_s_setprio(1);
        #pragma unroll
        for (int mb = 0; mb < 4; ++mb) {
          sacc[mb] = __builtin_amdgcn_mfma_f32_16x16x32_bf16(bk0[mb], aq0, sacc[mb], 0, 0, 0);
          sacc[mb] = __builtin_amdgcn_mfma_f32_16x16x32_bf16(bk1[mb], aq1, sacc[mb], 0, 0, 0);
        }
        __builtin_amdgcn_s_setprio(0);
      }

      // ---- mask (diag only) + in-register row max ----
      const bool diag = (kv0 == q0);
      float sv[4][4];
      float pm = -INFINITY;
      #pragma unroll
      for (int mb = 0; mb < 4; ++mb)
        #pragma unroll
        for (int j = 0; j < 4; ++j) {
          float v = sacc[mb][j];
          if (diag && (mb * 16 + fk * 4 + j > qloc)) v = -INFINITY;
          sv[mb][j] = v;
          pm = fmaxf(pm, v);
        }
      pm = fmaxf(pm, __shfl_xor(pm, 16, 64));
      pm = fmaxf(pm, __shfl_xor(pm, 32, 64));

      // ---- defer-max rescale (THR = 11.5 in log2 domain) ----
      if (__any(pm > m + 11.5f)) {
        const float mnew = fmaxf(m, pm);
        const float al = exp2f(m - mnew);
        m = mnew;
        lacc[0] *= al; lacc[1] *= al; lacc[2] *= al; lacc[3] *= al;
        #pragma unroll
        for (int db = 0; db < 4; ++db) {
          oacc[db][0] *= al; oacc[db][1] *= al;
          oacc[db][2] *= al; oacc[db][3] *= al;
        }
      }

      // ---- P = exp2(S-m), pack: in-lane B-fragments (V perm-placed) ----
      uint32_t rlo[4], rhi[4];
      #pragma unroll
      for (int mb = 0; mb < 4; ++mb) {
        float e0 = exp2f(sv[mb][0] - m);
        float e1 = exp2f(sv[mb][1] - m);
        float e2 = exp2f(sv[mb][2] - m);
        float e3 = exp2f(sv[mb][3] - m);
        CVTPK(rlo[mb], e0, e1);
        CVTPK(rhi[mb], e2, e3);
      }
      const bf16x8 pB0 = mk8w(rlo[0], rhi[0], rlo[1], rhi[1]);
      const bf16x8 pB1 = mk8w(rlo[2], rhi[2], rlo[3], rhi[3]);

      // ---- PV: O^T += V^T . P^T ; lsum via ones-MFMA ----
      unsigned long long t00, t01, t02, t03, t10, t11, t12, t13;
      unsigned long long t20, t21, t22, t23, t30, t31, t32, t33;
      TRREAD(t00, "0");    TRREAD(t01, "128");  TRREAD(t02, "1024"); TRREAD(t03, "1152");
      TRREAD(t10, "2080"); TRREAD(t11, "2208"); TRREAD(t12, "3104"); TRREAD(t13, "3232");
      TRREAD(t20, "4160"); TRREAD(t21, "4288"); TRREAD(t22, "5184"); TRREAD(t23, "5312");
      TRREAD(t30, "6240"); TRREAD(t31, "6368"); TRREAD(t32, "7264"); TRREAD(t33, "7392");
      asm volatile("s_waitcnt lgkmcnt(0)" ::: "memory");
      __builtin_amdgcn_sched_barrier(0);
      __builtin_amdgcn_s_setprio(1);
      lacc = __builtin_amdgcn_mfma_f32_16x16x32_bf16(ones, pB0, lacc, 0, 0, 0);
      lacc = __builtin_amdgcn_mfma_f32_16x16x32_bf16(ones, pB1, lacc, 0, 0, 0);
      oacc[0] = __builtin_amdgcn_mfma_f32_16x16x32_bf16(mk8(t00, t01), pB0, oacc[0], 0, 0, 0);
      oacc[0] = __builtin_amdgcn_mfma_f32_16x16x32_bf16(mk8(t02, t03), pB1, oacc[0], 0, 0, 0);
      oacc[1] = __builtin_amdgcn_mfma_f32_16x16x32_bf16(mk8(t10, t11), pB0, oacc[1], 0, 0, 0);
      oacc[1] = __builtin_amdgcn_mfma_f32_16x16x32_bf16(mk8(t12, t13), pB1, oacc[1], 0, 0, 0);
      oacc[2] = __builtin_amdgcn_mfma_f32_16x16x32_bf16(mk8(t20, t21), pB0, oacc[2], 0, 0, 0);
      oacc[2] = __builtin_amdgcn_mfma_f32_16x16x32_bf16(mk8(t22, t23), pB1, oacc[2], 0, 0, 0);
      oacc[3] = __builtin_amdgcn_mfma_f32_16x16x32_bf16(mk8(t30, t31), pB0, oacc[3], 0, 0, 0);
      oacc[3] = __builtin_amdgcn_mfma_f32_16x16x32_bf16(mk8(t32, t33), pB1, oacc[3], 0, 0, 0);
      __builtin_amdgcn_s_setprio(0);
      __syncthreads();
    }

    // ---- epilogue: O^T -> O, one q-row per lane ----
    {
      const float linv = 1.0f / lacc[0];
      short* orow = O + (size_t)(b * TLEN + q0 + wave * 16 + fr) * EMBED + h * HD + fk * 4;
      #pragma unroll
      for (int db = 0; db < 4; ++db) {
        s16x4 o4 = { f2bf(oacc[db][0] * linv), f2bf(oacc[db][1] * linv),
                     f2bf(oacc[db][2] * linv), f2bf(oacc[db][3] * linv) };
        *(s16x4*)&orow[db * 16] = o4;
      }
    }
  }
#undef TRREAD
#undef CVTPK
}

// ---------------------------------------------------------------------------
extern "C" void kernel_launch(void* const* d_in, const int* in_sizes, int n_in,
                              void* d_out, int out_size, void* d_ws, size_t ws_size,
                              hipStream_t stream) {
  const float* x  = (const float*)d_in[0];
  const float* Wq = (const float*)d_in[1];
  const float* bq = (const float*)d_in[2];
  const float* Wk = (const float*)d_in[3];
  const float* bk = (const float*)d_in[4];
  const float* Wv = (const float*)d_in[5];
  const float* bv = (const float*)d_in[6];
  const float* Wo = (const float*)d_in[7];
  const float* bo = (const float*)d_in[8];
  float* out = (float*)d_out;

  char* ws = (char*)d_ws;
  short* xb    = (short*)(ws);               // 16,777,216
  short* WqkvT = (short*)(ws + 16777216);    // 12,582,912
  short* WoT   = (short*)(ws + 29360128);    //  8,388,608
  short* QKV   = (short*)(ws + 37748736);    // 25,165,824
  short* Ob    = (short*)(ws);               // alias xb (dead after QKV GEMM)
  float2* tab  = (float2*)d_out;             // 512 KB scratch; overwritten at end

  // one fused prep launch: transposes + cast + rope table
  prep_kernel<<<18688, 256, 0, stream>>>(Wq, Wk, Wv, Wo, x, WqkvT, WoT, xb, tab);

  // fused QKV projection (plain epilogue)
  gemm_bt<false, true><<<dim3(QKVN / 128, MROWS / 128), 256, 0, stream>>>(
      xb, WqkvT, bq, bk, bv, QKV, QKVN);

  // single vectorized RoPE pass over Q+K region (Q scaled into exp2 domain)
  rope_fused_kernel<<<(MROWS * 320) / 256, 256, 0, stream>>>(QKV, tab);

  attn_kernel<<<dim3(16, BSZ * NH), 256, 0, stream>>>(
      QKV, QKV + 2048, QKV + 2560, Ob);

  gemm_bt<true, false><<<dim3(EMBED / 128, MROWS / 128), 256, 0, stream>>>(
      Ob, WoT, bo, bo, bo, out, EMBED);
}

// Round 25
// 226.108 us; speedup vs baseline: 1.0835x; 1.0107x over previous
//
#include <hip/hip_runtime.h>
#include <hip/hip_bf16.h>
#include <stdint.h>
#include <stddef.h>

#define EMBED 2048
#define TLEN  2048
#define BSZ   2
#define NH    32
#define NKV   8
#define HD    64
#define MROWS (BSZ*TLEN)   // 4096
#define KVD   (NKV*HD)     // 512
#define QKVN  3072         // fused QKV column extent / row stride

typedef __attribute__((ext_vector_type(8))) short   s16x8;
typedef __attribute__((ext_vector_type(4))) short   s16x4;
typedef __attribute__((ext_vector_type(8))) __bf16  bf16x8;
typedef __attribute__((ext_vector_type(4))) float   f32x4;
typedef __attribute__((ext_vector_type(2))) unsigned long long u64x2;
typedef __attribute__((ext_vector_type(4))) uint32_t u32x4;

static __device__ __forceinline__ float bf2f(short u) {
  union { float f; uint32_t i; } c; c.i = ((uint32_t)(uint16_t)u) << 16; return c.f;
}
static __device__ __forceinline__ short f2bf(float f) {
  union { float f; uint32_t i; } c; c.f = f;
  uint32_t x = c.i;
  uint32_t r = (x + 0x7fffu + ((x >> 16) & 1u)) >> 16;  // RNE
  return (short)(uint16_t)r;
}
static __device__ __forceinline__ bf16x8 as_bf16x8(s16x8 s) {
  return __builtin_bit_cast(bf16x8, s);
}
static __device__ __forceinline__ bf16x8 mk8(unsigned long long a, unsigned long long b) {
  u64x2 t; t.x = a; t.y = b;
  return __builtin_bit_cast(bf16x8, t);
}
static __device__ __forceinline__ bf16x8 mk8w(uint32_t w0, uint32_t w1,
                                              uint32_t w2, uint32_t w3) {
  u32x4 t; t.x = w0; t.y = w1; t.z = w2; t.w = w3;
  return __builtin_bit_cast(bf16x8, t);
}

// ---------------------------------------------------------------------------
// Fused prep: all weight transposes + x cast + rope table in ONE launch.
__device__ __forceinline__ void transpose_tile(
    const float* __restrict__ W, short* __restrict__ Wt, int N,
    int bx, int by, int tx, int ty) {
  __shared__ float tile[32][33];
  const int n0 = bx * 32, k0 = by * 32;
  #pragma unroll
  for (int i = 0; i < 32; i += 8)
    tile[ty + i][tx] = W[(size_t)(k0 + ty + i) * N + n0 + tx];
  __syncthreads();
  #pragma unroll
  for (int i = 0; i < 32; i += 8)
    Wt[(size_t)(n0 + ty + i) * 2048 + k0 + tx] = f2bf(tile[tx][ty + i]);
}

__global__ __launch_bounds__(256) void prep_kernel(
    const float* __restrict__ Wq, const float* __restrict__ Wk,
    const float* __restrict__ Wv, const float* __restrict__ Wo,
    const float* __restrict__ x,
    short* __restrict__ WqkvT, short* __restrict__ WoT,
    short* __restrict__ xb, float2* __restrict__ tab) {
  const int bid = blockIdx.x;
  const int tid = threadIdx.x;
  const int tx = tid & 31, ty = tid >> 5;
  if (bid < 4096) {
    transpose_tile(Wq, WqkvT, 2048, bid & 63, bid >> 6, tx, ty);
  } else if (bid < 5120) {
    const int l = bid - 4096;
    transpose_tile(Wk, WqkvT + (size_t)2048 * 2048, 512, l & 15, l >> 4, tx, ty);
  } else if (bid < 6144) {
    const int l = bid - 5120;
    transpose_tile(Wv, WqkvT + (size_t)2560 * 2048, 512, l & 15, l >> 4, tx, ty);
  } else if (bid < 10240) {
    const int l = bid - 6144;
    transpose_tile(Wo, WoT, 2048, l & 63, l >> 6, tx, ty);
  } else if (bid < 18432) {
    const int i = ((bid - 10240) * 256 + tid) * 4;
    f32x4 v = *(const f32x4*)(x + i);
    s16x4 o = { f2bf(v.x), f2bf(v.y), f2bf(v.z), f2bf(v.w) };
    *(s16x4*)(xb + i) = o;
  } else {
    const int idx = (bid - 18432) * 256 + tid;    // 0..65535
    const int t = idx >> 5, i = idx & 31;
    float ang = (float)t * powf(10000.0f, -(float)i / 32.0f);
    float c, s;
    sincosf(ang, &c, &s);
    tab[idx] = make_float2(c, s);
  }
}

// ---------------------------------------------------------------------------
// Vectorized RoPE over the K region only (cols [2048,2560) of each 3072-row).
// One thread = 8 shorts = 4 interleaved pairs; inverse rotation (np ref
// convention, verified R11). Q-rope is fused into the attention Q-load.
__global__ __launch_bounds__(256) void rope_k_kernel(
    short* __restrict__ QKV, const float2* __restrict__ tab) {
  const int idx = blockIdx.x * 256 + threadIdx.x;   // 0 .. 4096*64-1
  const int row = idx >> 6;
  const int c8 = 2048 + (idx & 63) * 8;
  const int t = row & (TLEN - 1);
  const int i0 = (c8 & 63) >> 1;                    // multiple of 4
  const float4* tp = (const float4*)&tab[(t << 5) + i0];
  const float4 cs01 = tp[0], cs23 = tp[1];
  short* p = QKV + (size_t)row * QKVN + c8;
  s16x8 v = *(const s16x8*)p;
  const float e0 = bf2f(v[0]), o0 = bf2f(v[1]), e1 = bf2f(v[2]), o1 = bf2f(v[3]);
  const float e2 = bf2f(v[4]), o2 = bf2f(v[5]), e3 = bf2f(v[6]), o3 = bf2f(v[7]);
  s16x8 r;
  r[0] = f2bf(e0 * cs01.x + o0 * cs01.y);
  r[1] = f2bf(o0 * cs01.x - e0 * cs01.y);
  r[2] = f2bf(e1 * cs01.z + o1 * cs01.w);
  r[3] = f2bf(o1 * cs01.z - e1 * cs01.w);
  r[4] = f2bf(e2 * cs23.x + o2 * cs23.y);
  r[5] = f2bf(o2 * cs23.x - e2 * cs23.y);
  r[6] = f2bf(e3 * cs23.z + o3 * cs23.w);
  r[7] = f2bf(o3 * cs23.z - e3 * cs23.w);
  *(s16x8*)p = r;
}

// ---------------------------------------------------------------------------
// C[M=4096][colN] = A[4096][2048] @ Bt[colN][2048]^T + bias; row stride ldc.
// 128x128 tile, BK=32, 4 waves, global_load_lds width=16 staging.
// Plain epilogue (R16-proven ~860 TF structure).
template<bool OUT_F32, bool TRIPLE_BIAS>
__global__ __launch_bounds__(256) void gemm_bt(
    const short* __restrict__ A, const short* __restrict__ Bt,
    const float* __restrict__ b0, const float* __restrict__ b1,
    const float* __restrict__ b2, void* __restrict__ Cout, int ldc) {
  const int K = 2048;
  __shared__ __align__(16) short As[128 * 32];
  __shared__ __align__(16) short Bs[128 * 32];
  int bn = blockIdx.x, bm = blockIdx.y;
  int tid = threadIdx.x;
  int lane = tid & 63, wave = tid >> 6;
  int wr = wave >> 1, wc = wave & 1;
  int fr = lane & 15, fk = lane >> 4;
  f32x4 acc[4][4] = {};
  const short* Ab = A + (size_t)bm * 128 * K;
  const short* Bb = Bt + (size_t)bn * 128 * K;
  for (int kt = 0; kt < K; kt += 32) {
    #pragma unroll
    for (int ii = 0; ii < 2; ++ii) {
      const int i = wave * 2 + ii;
      const int r = i * 16 + (lane >> 2);
      const int c = lane & 3;
      const size_t go = (size_t)r * K + kt + c * 8;
      __builtin_amdgcn_global_load_lds(
          (const __attribute__((address_space(1))) void*)(Ab + go),
          (__attribute__((address_space(3))) void*)&As[i * 512], 16, 0, 0);
      __builtin_amdgcn_global_load_lds(
          (const __attribute__((address_space(1))) void*)(Bb + go),
          (__attribute__((address_space(3))) void*)&Bs[i * 512], 16, 0, 0);
    }
    __syncthreads();
    bf16x8 af[4], bfr[4];
    #pragma unroll
    for (int m = 0; m < 4; ++m)
      af[m] = as_bf16x8(*(const s16x8*)&As[(wr * 64 + m * 16 + fr) * 32 + fk * 8]);
    #pragma unroll
    for (int n = 0; n < 4; ++n)
      bfr[n] = as_bf16x8(*(const s16x8*)&Bs[(wc * 64 + n * 16 + fr) * 32 + fk * 8]);
    __builtin_amdgcn_s_setprio(1);
    #pragma unroll
    for (int m = 0; m < 4; ++m)
      #pragma unroll
      for (int n = 0; n < 4; ++n)
        acc[m][n] = __builtin_amdgcn_mfma_f32_16x16x32_bf16(af[m], bfr[n], acc[m][n], 0, 0, 0);
    __builtin_amdgcn_s_setprio(0);
    __syncthreads();
  }
  int row0 = bm * 128 + wr * 64;
  int col0 = bn * 128 + wc * 64;
  #pragma unroll
  for (int n = 0; n < 4; ++n) {
    int col = col0 + n * 16 + fr;
    float bv;
    if constexpr (TRIPLE_BIAS)
      bv = (col < 2048) ? b0[col] : ((col < 2560) ? b1[col - 2048] : b2[col - 2560]);
    else
      bv = b0[col];
    #pragma unroll
    for (int m = 0; m < 4; ++m)
      #pragma unroll
      for (int j = 0; j < 4; ++j) {
        int row = row0 + m * 16 + fk * 4 + j;
        float v = acc[m][n][j] + bv;
        if constexpr (OUT_F32) ((float*)Cout)[(size_t)row * ldc + col] = v;
        else                   ((short*)Cout)[(size_t)row * ldc + col] = f2bf(v);
      }
  }
}

// ---------------------------------------------------------------------------
// Flash attention (R20/R24 structure, 93.5 us measured) + FUSED Q-RoPE:
// each block loads its Q fragment once; the interleaved pairs (2u,2u+1) are
// in-lane (lane holds 8 consecutive d), so the inverse rotation + exp2-domain
// scale fold into the prologue at ~40 VALU/block (amortized over 33 tiles).
// 4 waves, 64 q-rows/block, KVBLK=64, q-tile pair (p, 31-p). Swapped-operand
// S^T = mfma(K,Q); K staged in LDS; V staged with PERMUTED subtile placement
// so each lane's cvt_pk words ARE the P^T B-fragments; PV via tr_read.
// exp2 softmax, defer-max, ones-MFMA row sums.
__global__ __launch_bounds__(256) void attn_kernel(
    const short* __restrict__ Q, const short* __restrict__ Kx,
    const short* __restrict__ Vx, short* __restrict__ O,
    const float2* __restrict__ tab) {
  const int pr = blockIdx.x;           // 0..15
  const int bh = blockIdx.y;           // 0..63
  const int b = bh >> 5, h = bh & 31, kvh = h >> 2;
  const int tid = threadIdx.x;
  const int lane = tid & 63, wave = tid >> 6;
  const int fr = lane & 15, fk = lane >> 4;

  __shared__ __align__(16) short Ks[64][72];    // [kpos][d], 2-way padded
  __shared__ __align__(16) short VS[4 * 1040];  // tr-read subtiled V (permuted)

  const short* Kbase = Kx + (size_t)b * TLEN * QKVN + kvh * HD;
  const short* Vbase = Vx + (size_t)b * TLEN * QKVN + kvh * HD;

  const int srow = tid >> 3;           // 0..31
  const int scb  = (tid & 7) << 3;
  const int vd0  = scb >> 4;
  const int vco  = scb & 15;
  // permuted slot for kpos r (r<32): p = ((r>>2)&3)<<3 | ((r>>4)&1)<<2 | (r&3)
  const int p0 = (((srow >> 2) & 3) << 3) | (((srow >> 4) & 1) << 2) | (srow & 3);
  const int vaddr0 = vd0 * 1040 + ((p0 >> 2) << 6) + ((p0 & 3) << 4) + vco;
  const int vaddr1 = vaddr0 + 512;     // r+32 -> slot p+32
  const unsigned trb = (unsigned)(unsigned long long)&VS[fk * 128 + fr * 4];
  const bf16x8 ones = mk8(0x3F803F803F803F80ULL, 0x3F803F803F803F80ULL);
  const float QSC = 0.125f * 1.44269504088896340736f;

#define TRREAD(dst, OFF) asm volatile("ds_read_b64_tr_b16 %0, %1 offset:" OFF \
    : "=v"(dst) : "v"(trb) : "memory")
#define CVTPK(d, lo, hi) asm volatile("v_cvt_pk_bf16_f32 %0, %1, %2" \
    : "=v"(d) : "v"(lo), "v"(hi))

  #pragma unroll 1
  for (int rep = 0; rep < 2; ++rep) {
    const int qt = rep ? (31 - pr) : pr;
    const int q0 = qt * 64;
    const int tpos = q0 + wave * 16 + fr;          // position (row & 2047)
    const short* Qrow = Q + (size_t)(b * TLEN + tpos) * QKVN + h * HD;
    // ---- fused Q-RoPE: in-lane pair rotation + exp2-domain scale ----
    bf16x8 aq0, aq1;
    {
      const s16x8 q0r = *(const s16x8*)&Qrow[fk * 8];
      const s16x8 q1r = *(const s16x8*)&Qrow[32 + fk * 8];
      const float2* tq0 = &tab[(tpos << 5) + fk * 4];        // pairs fk*4..+3
      const float2* tq1 = &tab[(tpos << 5) + 16 + fk * 4];   // pairs 16+fk*4..
      s16x8 a0, a1;
      #pragma unroll
      for (int u = 0; u < 4; ++u) {
        float2 cs = tq0[u];
        float e = bf2f(q0r[2 * u]), o = bf2f(q0r[2 * u + 1]);
        a0[2 * u]     = f2bf((e * cs.x + o * cs.y) * QSC);
        a0[2 * u + 1] = f2bf((o * cs.x - e * cs.y) * QSC);
        cs = tq1[u];
        e = bf2f(q1r[2 * u]); o = bf2f(q1r[2 * u + 1]);
        a1[2 * u]     = f2bf((e * cs.x + o * cs.y) * QSC);
        a1[2 * u + 1] = f2bf((o * cs.x - e * cs.y) * QSC);
      }
      aq0 = as_bf16x8(a0);
      aq1 = as_bf16x8(a1);
    }
    f32x4 oacc[4] = {};
    f32x4 lacc = {};
    float m = -INFINITY;
    const int qloc = wave * 16 + fr;

    for (int kv0 = 0; kv0 <= q0; kv0 += 64) {
      // ---- stage K (row-major padded) and V (permuted subtiles) ----
      #pragma unroll
      for (int it = 0; it < 2; ++it) {
        const int r = srow + it * 32;
        const size_t gro = (size_t)(kv0 + r) * QKVN + scb;
        *(s16x8*)&Ks[r][scb] = *(const s16x8*)&Kbase[gro];
        s16x8 vv = *(const s16x8*)&Vbase[gro];
        *(s16x8*)&VS[it ? vaddr1 : vaddr0] = vv;
      }
      __syncthreads();

      // ---- S^T = K Q^T : 4 m-tiles (k-blocks of 16) ----
      f32x4 sacc[4] = {};
      {
        bf16x8 bk0[4], bk1[4];
        #pragma unroll
        for (int mb = 0; mb < 4; ++mb) {
          bk0[mb] = as_bf16x8(*(const s16x8*)&Ks[mb * 16 + fr][fk * 8]);
          bk1[mb] = as_bf16x8(*(const s16x8*)&Ks[mb * 16 + fr][32 + fk * 8]);
        }
        __builtin_amdgcn_s_setprio(1);
        #pragma unroll
        for (int mb = 0; mb < 4; ++mb) {
          sacc[mb] = __builtin_amdgcn_mfma_f32_16x16x32_bf16(bk0[mb], aq0, sacc[mb], 0, 0, 0);
          sacc[mb] = __builtin_amdgcn_mfma_f32_16x16x32_bf16(bk1[mb], aq1, sacc[mb], 0, 0, 0);
        }
        __builtin_amdgcn_s_setprio(0);
      }

      // ---- mask (diag only) + in-register row max ----
      const bool diag = (kv0 == q0);
      float sv[4][4];
      float pm = -INFINITY;
      #pragma unroll
      for (int mb = 0; mb < 4; ++mb)
        #pragma unroll
        for (int j = 0; j < 4; ++j) {
          float v = sacc[mb][j];
          if (diag && (mb * 16 + fk * 4 + j > qloc)) v = -INFINITY;
          sv[mb][j] = v;
          pm = fmaxf(pm, v);
        }
      pm = fmaxf(pm, __shfl_xor(pm, 16, 64));
      pm = fmaxf(pm, __shfl_xor(pm, 32, 64));

      // ---- defer-max rescale (THR = 11.5 in log2 domain) ----
      if (__any(pm > m + 11.5f)) {
        const float mnew = fmaxf(m, pm);
        const float al = exp2f(m - mnew);
        m = mnew;
        lacc[0] *= al; lacc[1] *= al; lacc[2] *= al; lacc[3] *= al;
        #pragma unroll
        for (int db = 0; db < 4; ++db) {
          oacc[db][0] *= al; oacc[db][1] *= al;
          oacc[db][2] *= al; oacc[db][3] *= al;
        }
      }

      // ---- P = exp2(S-m), pack: in-lane B-fragments (V perm-placed) ----
      uint32_t rlo[4], rhi[4];
      #pragma unroll
      for (int mb = 0; mb < 4; ++mb) {
        float e0 = exp2f(sv[mb][0] - m);
        float e1 = exp2f(sv[mb][1] - m);
        float e2 = exp2f(sv[mb][2] - m);
        float e3 = exp2f(sv[mb][3] - m);
        CVTPK(rlo[mb], e0, e1);
        CVTPK(rhi[mb], e2, e3);
      }
      const bf16x8 pB0 = mk8w(rlo[0], rhi[0], rlo[1], rhi[1]);
      const bf16x8 pB1 = mk8w(rlo[2], rhi[2], rlo[3], rhi[3]);

      // ---- PV: O^T += V^T . P^T ; lsum via ones-MFMA ----
      unsigned long long t00, t01, t02, t03, t10, t11, t12, t13;
      unsigned long long t20, t21, t22, t23, t30, t31, t32, t33;
      TRREAD(t00, "0");    TRREAD(t01, "128");  TRREAD(t02, "1024"); TRREAD(t03, "1152");
      TRREAD(t10, "2080"); TRREAD(t11, "2208"); TRREAD(t12, "3104"); TRREAD(t13, "3232");
      TRREAD(t20, "4160"); TRREAD(t21, "4288"); TRREAD(t22, "5184"); TRREAD(t23, "5312");
      TRREAD(t30, "6240"); TRREAD(t31, "6368"); TRREAD(t32, "7264"); TRREAD(t33, "7392");
      asm volatile("s_waitcnt lgkmcnt(0)" ::: "memory");
      __builtin_amdgcn_sched_barrier(0);
      __builtin_amdgcn_s_setprio(1);
      lacc = __builtin_amdgcn_mfma_f32_16x16x32_bf16(ones, pB0, lacc, 0, 0, 0);
      lacc = __builtin_amdgcn_mfma_f32_16x16x32_bf16(ones, pB1, lacc, 0, 0, 0);
      oacc[0] = __builtin_amdgcn_mfma_f32_16x16x32_bf16(mk8(t00, t01), pB0, oacc[0], 0, 0, 0);
      oacc[0] = __builtin_amdgcn_mfma_f32_16x16x32_bf16(mk8(t02, t03), pB1, oacc[0], 0, 0, 0);
      oacc[1] = __builtin_amdgcn_mfma_f32_16x16x32_bf16(mk8(t10, t11), pB0, oacc[1], 0, 0, 0);
      oacc[1] = __builtin_amdgcn_mfma_f32_16x16x32_bf16(mk8(t12, t13), pB1, oacc[1], 0, 0, 0);
      oacc[2] = __builtin_amdgcn_mfma_f32_16x16x32_bf16(mk8(t20, t21), pB0, oacc[2], 0, 0, 0);
      oacc[2] = __builtin_amdgcn_mfma_f32_16x16x32_bf16(mk8(t22, t23), pB1, oacc[2], 0, 0, 0);
      oacc[3] = __builtin_amdgcn_mfma_f32_16x16x32_bf16(mk8(t30, t31), pB0, oacc[3], 0, 0, 0);
      oacc[3] = __builtin_amdgcn_mfma_f32_16x16x32_bf16(mk8(t32, t33), pB1, oacc[3], 0, 0, 0);
      __builtin_amdgcn_s_setprio(0);
      __syncthreads();
    }

    // ---- epilogue: O^T -> O, one q-row per lane ----
    {
      const float linv = 1.0f / lacc[0];
      short* orow = O + (size_t)(b * TLEN + q0 + wave * 16 + fr) * EMBED + h * HD + fk * 4;
      #pragma unroll
      for (int db = 0; db < 4; ++db) {
        s16x4 o4 = { f2bf(oacc[db][0] * linv), f2bf(oacc[db][1] * linv),
                     f2bf(oacc[db][2] * linv), f2bf(oacc[db][3] * linv) };
        *(s16x4*)&orow[db * 16] = o4;
      }
    }
  }
#undef TRREAD
#undef CVTPK
}

// ---------------------------------------------------------------------------
extern "C" void kernel_launch(void* const* d_in, const int* in_sizes, int n_in,
                              void* d_out, int out_size, void* d_ws, size_t ws_size,
                              hipStream_t stream) {
  const float* x  = (const float*)d_in[0];
  const float* Wq = (const float*)d_in[1];
  const float* bq = (const float*)d_in[2];
  const float* Wk = (const float*)d_in[3];
  const float* bk = (const float*)d_in[4];
  const float* Wv = (const float*)d_in[5];
  const float* bv = (const float*)d_in[6];
  const float* Wo = (const float*)d_in[7];
  const float* bo = (const float*)d_in[8];
  float* out = (float*)d_out;

  char* ws = (char*)d_ws;
  short* xb    = (short*)(ws);               // 16,777,216
  short* WqkvT = (short*)(ws + 16777216);    // 12,582,912
  short* WoT   = (short*)(ws + 29360128);    //  8,388,608
  short* QKV   = (short*)(ws + 37748736);    // 25,165,824
  short* Ob    = (short*)(ws);               // alias xb (dead after QKV GEMM)
  float2* tab  = (float2*)d_out;             // 512 KB scratch; overwritten at end

  // one fused prep launch: transposes + cast + rope table
  prep_kernel<<<18688, 256, 0, stream>>>(Wq, Wk, Wv, Wo, x, WqkvT, WoT, xb, tab);

  // fused QKV projection (plain epilogue)
  gemm_bt<false, true><<<dim3(QKVN / 128, MROWS / 128), 256, 0, stream>>>(
      xb, WqkvT, bq, bk, bv, QKV, QKVN);

  // RoPE on K region only (Q-rope fused into attention)
  rope_k_kernel<<<(MROWS * 64) / 256, 256, 0, stream>>>(QKV, tab);

  attn_kernel<<<dim3(16, BSZ * NH), 256, 0, stream>>>(
      QKV, QKV + 2048, QKV + 2560, Ob, tab);

  gemm_bt<true, false><<<dim3(EMBED / 128, MROWS / 128), 256, 0, stream>>>(
      Ob, WoT, bo, bo, bo, out, EMBED);
}